// Round 1
// 158.446 us; speedup vs baseline: 1.0668x; 1.0668x over previous
//
#include <hip/hip_runtime.h>

// LSTM_WP: B=4096 batch-1 LSTMs, T=H=128, input_size=1, fused MFMA-f16 recurrence.
// Round 11 (polish): keep the proven r8/r10 schedule (256 blocks x 16 batches,
// 8 waves, 1 barrier/step, split depth-2 MFMA chains, preact in MFMA shadow).
// New in this round — pure issue-count surgery:
//  (1) swapped MFMA operands: mfma(W, h, iv) -> D[gatecol][batch]. LDS h reads
//      are byte-identical (A/B layout symmetry); the 4 ew results per lane now
//      hit 4 consecutive h columns -> single ds_write_b64 instead of 4x b16.
//  (2) ew phase2 written in f32x2 / preact+merge in f32x4 vector form to get
//      v_pk_{add,mul,fma}_f32 (full-rate dual f32) -> ~40 fewer VALU/wave/step.
//  (3) cell state stored pre-scaled by 2log2e -> the dependent cn*K mul between
//      rcp and exp2 on the critical chain is gone; wm folded into an fma.
//  (4) prep_whh kernel folded into init (direct W_hh f32 -> scale -> cvt into
//      fragments) -> one launch instead of two, no inter-kernel serialization.

#define H   128
#define T   128
#define BLOCK 512
#define HSTRIDE 136     // f16 per h row: 272 B -> b128-aligned, 2-way banks (free)
#define XSTRIDE 20      // f32 per xs row: 80 B
#define LOG2E    1.44269504088896340736f
#define TWOLOG2E 2.88539008177792681472f

typedef _Float16 f16x8 __attribute__((ext_vector_type(8)));
typedef _Float16 f16x4 __attribute__((ext_vector_type(4)));
typedef float    f32x4 __attribute__((ext_vector_type(4)));
typedef float    f32x2 __attribute__((ext_vector_type(2)));

__device__ __forceinline__ float frcp(float v)  { return __builtin_amdgcn_rcpf(v); }
__device__ __forceinline__ float fexp2(float v) { return __builtin_amdgcn_exp2f(v); }

// ---- one LSTM step: 16 batches x this wave's 16 cols, transposed fragments ----
// D[row=gatecol-in-tile][col=batch]: lane(l15,q) holds gatecols hcol0..hcol0+3
// of batch l15. iv: preacts for THIS step (in); refilled for NEXT step (out).
__device__ __forceinline__ void lstm_step(const _Float16* __restrict__ hr,
                                          _Float16* __restrict__ hw,
                                          f32x4 iv[4], const float* xp_next,
                                          const f16x8 wf[4][4],
                                          const f32x4 wihv[4], const f32x4 biasv[4],
                                          f32x2 C[2], int l15, int q, int hcol0)
{
    // B-fragments (h): same addresses/bytes as the old A-read — 4x ds_read_b128
    const _Float16* ar = hr + l15 * HSTRIDE + q * 8;
    f16x8 af0 = *(const f16x8*)(ar);
    f16x8 af1 = *(const f16x8*)(ar + 32);
    f16x8 af2 = *(const f16x8*)(ar + 64);
    f16x8 af3 = *(const f16x8*)(ar + 96);

    // 8 independent depth-2 MFMA chains (r10 structure), W as the A operand
    const f32x4 zz = {0.f, 0.f, 0.f, 0.f};
    f32x4 lo[4], hi[4];
    #pragma unroll
    for (int g = 0; g < 4; ++g)
        lo[g] = __builtin_amdgcn_mfma_f32_16x16x32_f16(wf[g][0], af0, iv[g], 0, 0, 0);
    #pragma unroll
    for (int g = 0; g < 4; ++g)
        hi[g] = __builtin_amdgcn_mfma_f32_16x16x32_f16(wf[g][2], af2, zz, 0, 0, 0);
    #pragma unroll
    for (int g = 0; g < 4; ++g)
        lo[g] = __builtin_amdgcn_mfma_f32_16x16x32_f16(wf[g][1], af1, lo[g], 0, 0, 0);
    #pragma unroll
    for (int g = 0; g < 4; ++g)
        hi[g] = __builtin_amdgcn_mfma_f32_16x16x32_f16(wf[g][3], af3, hi[g], 0, 0, 0);

    // next step's preacts in the MFMA shadow: x[batch=l15] broadcast, pk_fma
    {
        float xv = xp_next[l15];
        f32x4 xb = {xv, xv, xv, xv};
        #pragma unroll
        for (int g = 0; g < 4; ++g)
            iv[g] = __builtin_elementwise_fma(xb, wihv[g], biasv[g]);
    }

    // merge halves (vector adds -> v_pk_add_f32)
    f32x4 acc[4];
    #pragma unroll
    for (int g = 0; g < 4; ++g)
        acc[g] = lo[g] + hi[g];

    // ---- ew phase 1: 16 independent exps (log2 domain) ----
    f32x2 Ei[2], Ef[2], Eg[2], Eo[2];
    #pragma unroll
    for (int p = 0; p < 2; ++p) {
        Ei[p] = (f32x2){ fexp2(-acc[0][2 * p]), fexp2(-acc[0][2 * p + 1]) };  // sig_i = 1/(1+Ei)
        Ef[p] = (f32x2){ fexp2(-acc[1][2 * p]), fexp2(-acc[1][2 * p + 1]) };  // sig_f = 1/(1+Ef)
        Eg[p] = (f32x2){ fexp2( acc[2][2 * p]), fexp2( acc[2][2 * p + 1]) };  // tanh_g = (Eg-1)/(Eg+1)
        Eo[p] = (f32x2){ fexp2(-acc[3][2 * p]), fexp2(-acc[3][2 * p + 1]) };  // sig_o = 1/(1+Eo)
    }

    // ---- ew phase 2: packed-f32 pairs; C kept pre-scaled by 2log2e ----
    const f32x2 one2 = {1.0f, 1.0f};
    const f32x2 k2   = { TWOLOG2E,  TWOLOG2E};
    const f32x2 mk2  = {-TWOLOG2E, -TWOLOG2E};
    f16x4 hh;
    #pragma unroll
    for (int p = 0; p < 2; ++p) {
        f32x2 u  = one2 + Ei[p];
        f32x2 v  = one2 + Ef[p];
        f32x2 w  = one2 + Eg[p];
        f32x2 wm = __builtin_elementwise_fma(Eg[p], k2, mk2);    // 2log2e*(Eg-1)
        f32x2 uw = u * w;
        // C' = [C*u*w + wm*v] / (v*u*w)  (already in 2log2e domain), one rcp
        f32x2 nm = __builtin_elementwise_fma(C[p], uw, wm * v);
        f32x2 dn = v * uw;
        f32x2 rd = { frcp(dn[0]), frcp(dn[1]) };
        f32x2 cn = nm * rd;
        C[p] = cn;
        f32x2 ec  = { fexp2(cn[0]), fexp2(cn[1]) };              // tanh(c') = (ec-1)/(ec+1)
        f32x2 den = (ec + one2) * (one2 + Eo[p]);
        f32x2 rh  = { frcp(den[0]), frcp(den[1]) };
        f32x2 hv  = (ec - one2) * rh;
        hh[2 * p]     = (_Float16)hv[0];
        hh[2 * p + 1] = (_Float16)hv[1];
    }
    // 4 consecutive cols of batch-row l15 -> one 8 B store (8 B aligned)
    *(f16x4*)(hw + l15 * HSTRIDE + hcol0) = hh;
}

__launch_bounds__(BLOCK, 2)
__global__ void lstm_fused_kernel(const float* __restrict__ x,
                                  const float* __restrict__ W_ih,
                                  const float* __restrict__ W_hh,
                                  const float* __restrict__ b_ih,
                                  const float* __restrict__ b_hh,
                                  const float* __restrict__ fc_W,
                                  const float* __restrict__ fc_b,
                                  float* __restrict__ out)
{
    __shared__ __align__(16) float xs[T + 1][XSTRIDE];           // +1 row: prefetch pad
    __shared__ __align__(16) _Float16 hb0[16 * HSTRIDE];         // h buffers (4.25 KB each)
    __shared__ __align__(16) _Float16 hb1[16 * HSTRIDE];

    const int tid  = threadIdx.x;
    const int wave = tid >> 6;          // column tile 0..7
    const int lane = tid & 63;
    const int l15  = lane & 15;         // batch row (B-operand col)
    const int q    = lane >> 4;         // 0..3
    const int hcol0 = wave * 16 + q * 4;// first of this lane's 4 hidden cols

    // ---- stage x: [b][t] global -> xs[t][b] (16 batches x 128 t) ----
    {
        const int t0 = tid & 127;
        const int bb = tid >> 7;        // 0..3
        const float* xb = x + (size_t)blockIdx.x * (16 * T);
        xs[t0][bb]      = xb[bb * T + t0];
        xs[t0][bb + 4]  = xb[(bb + 4) * T + t0];
        xs[t0][bb + 8]  = xb[(bb + 8) * T + t0];
        xs[t0][bb + 12] = xb[(bb + 12) * T + t0];
    }
    for (int i = tid; i < 16 * HSTRIDE; i += BLOCK)              // h0 = 0
        hb0[i] = (_Float16)0.0f;

    // ---- weights: build fragments directly from W_hh (prep kernel folded in).
    // Fragment data layout is identical to the old wfrag; it is now the MFMA
    // A operand: lane(l15,q), kc -> W_hh[g*H + wave*16 + l15][kc*32+q*8 ..+8].
    f16x8 wf[4][4];
    f32x4 wihv[4], biasv[4];
    #pragma unroll
    for (int g = 0; g < 4; ++g) {
        const float s = (g == 2) ? TWOLOG2E : LOG2E;
        #pragma unroll
        for (int kc = 0; kc < 4; ++kc) {
            const float* src = W_hh + (size_t)(g * H + wave * 16 + l15) * H + kc * 32 + q * 8;
            float4 w0 = *(const float4*)src;
            float4 w1 = *(const float4*)(src + 4);
            f16x8 f;
            f[0] = (_Float16)(w0.x * s); f[1] = (_Float16)(w0.y * s);
            f[2] = (_Float16)(w0.z * s); f[3] = (_Float16)(w0.w * s);
            f[4] = (_Float16)(w1.x * s); f[5] = (_Float16)(w1.y * s);
            f[6] = (_Float16)(w1.z * s); f[7] = (_Float16)(w1.w * s);
            wf[g][kc] = f;
        }
        #pragma unroll
        for (int r = 0; r < 4; ++r) {   // per-lane input-proj coeffs for its 4 cols
            const int n = g * H + hcol0 + r;
            wihv[g][r]  = W_ih[n] * s;
            biasv[g][r] = (b_ih[n] + b_hh[n]) * s;
        }
    }

    f32x2 C[2] = {{0.f, 0.f}, {0.f, 0.f}};   // cell state, pre-scaled by 2log2e

    __syncthreads();

    // preacts for t=0
    f32x4 iv[4];
    {
        float xv = xs[0][l15];
        f32x4 xb = {xv, xv, xv, xv};
        #pragma unroll
        for (int g = 0; g < 4; ++g)
            iv[g] = __builtin_elementwise_fma(xb, wihv[g], biasv[g]);
    }
    const float* xpn = &xs[1][0];       // next-step preact source

    // ---- recurrence: unrolled x2, compile-time buffer bases, 1 barrier/step ----
    #pragma unroll 1
    for (int t2 = 0; t2 < T / 2; ++t2) {
        lstm_step(hb0, hb1, iv, xpn, wf, wihv, biasv, C, l15, q, hcol0);
        xpn += XSTRIDE;
        __syncthreads();
        lstm_step(hb1, hb0, iv, xpn, wf, wihv, biasv, C, l15, q, hcol0);
        xpn += XSTRIDE;
        __syncthreads();
    }
    // T even -> final h lives in hb0

    // ---- epilogue: out[b] = fc_b + sum_j fc_W[j] * hT[b][j] ----
    if (tid < 256) {
        const int b    = tid >> 4;      // 0..15
        const int part = tid & 15;
        const _Float16* hrow = &hb0[b * HSTRIDE];
        float s = 0.0f;
        #pragma unroll
        for (int i = 0; i < 8; ++i) {
            const int j = part * 8 + i;
            s += fc_W[j] * (float)hrow[j];
        }
        s += __shfl_xor(s, 8, 16);
        s += __shfl_xor(s, 4, 16);
        s += __shfl_xor(s, 2, 16);
        s += __shfl_xor(s, 1, 16);
        if (part == 0)
            out[blockIdx.x * 16 + b] = s + fc_b[0];
    }
}

extern "C" void kernel_launch(void* const* d_in, const int* in_sizes, int n_in,
                              void* d_out, int out_size, void* d_ws, size_t ws_size,
                              hipStream_t stream)
{
    const float* x    = (const float*)d_in[0];
    const float* W_ih = (const float*)d_in[1];
    const float* W_hh = (const float*)d_in[2];
    const float* b_ih = (const float*)d_in[3];
    const float* b_hh = (const float*)d_in[4];
    const float* fc_W = (const float*)d_in[5];
    const float* fc_b = (const float*)d_in[6];
    float* out = (float*)d_out;
    (void)d_ws; (void)ws_size;

    const int B = in_sizes[0] / H;         // 4096 chunks
    dim3 grid(B / 16);                     // 256 blocks -> 1 per CU
    dim3 block(BLOCK);                     // 8 waves, 2 per SIMD
    hipLaunchKernelGGL(lstm_fused_kernel, grid, block, 0, stream,
                       x, W_ih, W_hh, b_ih, b_hh, fc_W, fc_b, out);
}